// Round 13
// baseline (245.648 us; speedup 1.0000x reference)
//
#include <hip/hip_runtime.h>
#include <hip/hip_bf16.h>

#define NB 256
#define NR 100
#define ND 6168
#define DP 6272            // 196 * 32
#define NH 128
#define NC 100
#define NW 196             // bit-words (= ktiles) per row
#define ROWW 196
#define ROWB 784           // bytes of bits per row
#define BITS_B (NR * ROWB) // 78400 per b
#define CPR 25             // 256-int chunks per row
#define TOTAL_CHUNKS (NB * NR * CPR)  // 640000
#define CPW 79             // contiguous chunks per wave (8192 waves)
#define W1T_BYTES ((size_t)NH * DP * 2)
#define XBITS_BYTES ((size_t)NB * ROWW * 4 + 1024)

// gemm LDS map
#define L_XB 0
#define L_BITS 1024
#define L_TOT (1024 + 77 * 1024)   // 79,872 B

typedef __attribute__((ext_vector_type(8))) __bf16 bf16x8;
typedef __attribute__((ext_vector_type(4))) float f32x4;
typedef __attribute__((ext_vector_type(4))) int i32x4;
typedef __attribute__((ext_vector_type(4))) unsigned int u32x4;
typedef unsigned int u32;
typedef unsigned long long u64;

typedef const __attribute__((address_space(1))) u32* gas_ptr;
typedef __attribute__((address_space(3))) u32* las_ptr;

__device__ __forceinline__ void gload16(const void* g, void* l) {
  __builtin_amdgcn_global_load_lds((gas_ptr)g, (las_ptr)l, 16, 0, 0);
}

// ---------- prep 1: W1 (ND,NH) f32 -> W1T (NH, DP) bf16, sigma-permuted ----------
// W1T[h][kbase+dd] = W1[kbase+sigma(dd)][h], sigma(dd) = (dd&7)*4 + (dd>>3):
// matches the ballot bit order of A (validated R11/R12).
__global__ void prep_w1t(const float* __restrict__ W1, __hip_bfloat16* __restrict__ W1T) {
  __shared__ float tile[32][NH + 1];
  const int d0 = blockIdx.x * 32;
  const int t = threadIdx.x;
#pragma unroll
  for (int p = 0; p < 16; ++p) {
    int idx = p * 256 + t;
    int dd = idx >> 7;
    int h  = idx & 127;
    int d  = d0 + dd;
    tile[dd][h] = (d < ND) ? W1[d * NH + h] : 0.f;
  }
  __syncthreads();
#pragma unroll
  for (int p = 0; p < 16; ++p) {
    int idx = p * 256 + t;
    int h  = idx >> 5;
    int dd = idx & 31;
    int sd = (dd & 7) * 4 + (dd >> 3);      // sigma
    W1T[h * DP + d0 + dd] = __float2bfloat16(tile[sd][h]);
  }
}

// ---------- ballot pack: one 256-int chunk -> 8 sigma-ordered words ----------
#define PACK_CHUNK_V(V, DSTROW, WJBASE)                                        \
  do {                                                                         \
    u64 M0 = __ballot(((V)[0] & 1) != 0);                                      \
    u64 M1 = __ballot(((V)[1] & 1) != 0);                                      \
    u64 M2 = __ballot(((V)[2] & 1) != 0);                                      \
    u64 M3 = __ballot(((V)[3] & 1) != 0);                                      \
    if (lane < 8) {                                                            \
      int wj = (WJBASE) + lane;                                                \
      if (wj < ROWW) {                                                         \
        int sh = 8 * lane;                                                     \
        u32 b0 = (u32)(M0 >> sh) & 0xffu;                                      \
        u32 b1 = (u32)(M1 >> sh) & 0xffu;                                      \
        u32 b2 = (u32)(M2 >> sh) & 0xffu;                                      \
        u32 b3 = (u32)(M3 >> sh) & 0xffu;                                      \
        (DSTROW)[wj] = b0 | (b1 << 8) | (b2 << 16) | (b3 << 24);               \
      }                                                                        \
    }                                                                          \
  } while (0)

// ---------- prep 2: pack x -> xbits[b][196] (sigma order) ----------
__global__ void prep_xbits(const int* __restrict__ x, u32* __restrict__ xbits) {
  const int b    = blockIdx.x;
  const int lane = threadIdx.x & 63;
  const int wv   = threadIdx.x >> 6;
  const int* src = x + (size_t)b * ND;
  u32* dst = xbits + (size_t)b * ROWW;
  for (int c = wv; c < CPR; c += 4) {
    int k0 = c * 256 + lane * 4;
    int kc = (k0 + 4 <= ND) ? k0 : (ND - 4);
    i32x4 v = *(const i32x4*)(src + kc);
    PACK_CHUNK_V(v, dst, c * 8);
  }
}

// ---------- kernel 1: pack noise -> bits. Non-temporal, wave-contiguous runs ----------
// 2048 blocks x 256 thr = 8192 waves; wave wg owns chunks [wg*79, wg*79+79).
__global__ void pack_noise(const int* __restrict__ noise, u32* __restrict__ bits) {
  const int lane = threadIdx.x & 63;
  const int wg   = blockIdx.x * 4 + (threadIdx.x >> 6);   // 0..8191
  const int cw0  = wg * CPW;
  int r = cw0 / CPR;
  int c = cw0 - r * CPR;
  const int* src = noise + (size_t)r * ND;
  u32* dst = bits + (size_t)r * ROWW;
#pragma unroll 1
  for (int i = 0; i < CPW; ++i) {
    if (cw0 + i < TOTAL_CHUNKS) {
      int k0 = c * 256 + lane * 4;
      int kc = (k0 + 4 <= ND) ? k0 : (ND - 4);
      i32x4 v = __builtin_nontemporal_load((const i32x4*)(src + kc));
      PACK_CHUNK_V(v, dst, c * 8);
    }
    if (++c == CPR) { c = 0; ++r; src += ND; dst += ROWW; }
  }
}

// ---------- kernel 2: barrier-free LDS-bit GEMM + fused epilogue (R11-validated) ----------
__launch_bounds__(512, 1)
__global__ void gemm(const u32* __restrict__ bits, const __hip_bfloat16* __restrict__ W1T,
                     const float* __restrict__ b1, const u32* __restrict__ xbits,
                     const float* __restrict__ W2, const float* __restrict__ b2,
                     float* __restrict__ out) {
  __shared__ __align__(16) char lds[L_TOT];
  const int tid  = threadIdx.x;
  const int lane = tid & 63;
  const int w    = tid >> 6;      // 0..7
  const int wm   = w >> 2;        // 0..1: rows wm*64 .. +64
  const int wn   = w & 3;         // 0..3: cols wn*32 .. +32
  const int lq   = lane >> 4;
  const int lm   = lane & 15;
  const int b    = blockIdx.x;

  // ---- prologue: stage bits (77 KB) + xbits (784 B) to LDS, one drain ----
  {
    const char* bb = (const char*)bits + (size_t)b * BITS_B;
    for (int c = w; c < 77; c += 8) {
      u32 off = (u32)(c * 1024 + lane * 16);
      if (off > BITS_B - 16) off = BITS_B - 16;    // tail dup -> junk rows only
      gload16(bb + off, lds + L_BITS + c * 1024);
    }
    // per-lane SOURCE (m104): lane*16 on global; dest gets HW lane*16.
    if (w == 0) gload16((const char*)(xbits + (size_t)b * ROWW) + lane * 16, lds + L_XB);
  }
  __syncthreads();   // the only barrier before the epilogue

  f32x4 acc[4][2] = {};
  int rcb[4];
#pragma unroll
  for (int mf = 0; mf < 4; ++mf) {
    int row = wm * 64 + mf * 16 + lm;
    rcb[mf] = ((row < NR) ? row : (NR - 1)) * ROWB;
  }
  const __hip_bfloat16* wsrcA = W1T + (size_t)(wn * 32 + lm) * DP + lq * 8;
  const __hip_bfloat16* wsrcB = W1T + (size_t)(wn * 32 + 16 + lm) * DP + lq * 8;
  const int lsh = lq * 8;

  auto BLOAD = [&](int t, bf16x8* Br) {
    Br[0] = *(const bf16x8*)(wsrcA + t * 32);
    Br[1] = *(const bf16x8*)(wsrcB + t * 32);
  };
  auto CONS = [&](int t, const bf16x8* Br) {
    u32 xw = *(const u32*)(lds + L_XB + t * 4);
#pragma unroll
    for (int mf = 0; mf < 4; ++mf) {
      u32 word = (*(const u32*)(lds + L_BITS + rcb[mf] + t * 4)) ^ xw;
      u32 by = (word >> lsh) & 0xffu;
      u32 p0 = ((by & 1u)  ? 0x3F80u : 0u) | ((by & 2u)   ? 0x3F800000u : 0u);
      u32 p1 = ((by & 4u)  ? 0x3F80u : 0u) | ((by & 8u)   ? 0x3F800000u : 0u);
      u32 p2 = ((by & 16u) ? 0x3F80u : 0u) | ((by & 32u)  ? 0x3F800000u : 0u);
      u32 p3 = ((by & 64u) ? 0x3F80u : 0u) | ((by & 128u) ? 0x3F800000u : 0u);
      u32x4 pk = {p0, p1, p2, p3};
      bf16x8 af = *(bf16x8*)&pk;
      acc[mf][0] = __builtin_amdgcn_mfma_f32_16x16x32_bf16(af, Br[0], acc[mf][0], 0, 0, 0);
      acc[mf][1] = __builtin_amdgcn_mfma_f32_16x16x32_bf16(af, Br[1], acc[mf][1], 0, 0, 0);
    }
  };

  bf16x8 Bc[2], Bn[2];
  BLOAD(0, Bc);
#pragma unroll 1
  for (int t = 0; t < NW; t += 2) {
    BLOAD(t + 1, Bn);
    CONS(t, Bc);
    BLOAD((t + 2 < NW) ? (t + 2) : (NW - 1), Bc);
    CONS(t + 1, Bn);
  }

  // ---- epilogue: mean over rows of tanh(acc + b1), fold through W2 ----
  __syncthreads();
  float* hpart = (float*)lds;            // [2][128] overlay
  float* hbar  = (float*)(lds + 1024);   // [128]
#pragma unroll
  for (int nf = 0; nf < 2; ++nf) {
    int hcol = wn * 32 + nf * 16 + lm;
    float bb = b1[hcol];
    float ssum = 0.f;
#pragma unroll
    for (int mf = 0; mf < 4; ++mf) {
#pragma unroll
      for (int rg = 0; rg < 4; ++rg) {
        int m = wm * 64 + mf * 16 + lq * 4 + rg;
        float tv = tanhf(acc[mf][nf][rg] + bb);
        ssum += (m < NR) ? tv : 0.f;
      }
    }
    ssum += __shfl_xor(ssum, 16, 64);
    ssum += __shfl_xor(ssum, 32, 64);
    if (lq == 0) hpart[wm * 128 + hcol] = ssum;
  }
  __syncthreads();
  if (tid < NH) hbar[tid] = (hpart[tid] + hpart[128 + tid]) * (1.0f / NR);
  __syncthreads();
  if (tid < NC) {
    float sacc = b2[tid];
#pragma unroll 8
    for (int h = 0; h < NH; ++h) sacc += hbar[h] * W2[h * NC + tid];
    out[b * NC + tid] = sacc;
  }
}

extern "C" void kernel_launch(void* const* d_in, const int* in_sizes, int n_in,
                              void* d_out, int out_size, void* d_ws, size_t ws_size,
                              hipStream_t stream) {
  (void)in_sizes; (void)n_in; (void)out_size; (void)ws_size;
  const int* x     = (const int*)d_in[0];
  const int* noise = (const int*)d_in[1];
  const float* W1  = (const float*)d_in[2];
  const float* b1  = (const float*)d_in[3];
  const float* W2  = (const float*)d_in[4];
  const float* b2  = (const float*)d_in[5];
  float* out = (float*)d_out;

  __hip_bfloat16* W1T = (__hip_bfloat16*)d_ws;
  u32* xbits = (u32*)((char*)d_ws + W1T_BYTES);
  u32* bits  = (u32*)((char*)d_ws + W1T_BYTES + XBITS_BYTES);

  prep_w1t<<<DP / 32, 256, 0, stream>>>(W1, W1T);
  prep_xbits<<<NB, 256, 0, stream>>>(x, xbits);
  pack_noise<<<2048, 256, 0, stream>>>(noise, bits);
  gemm<<<NB, 512, 0, stream>>>(bits, W1T, b1, xbits, W2, b2, out);
}

// Round 14
// 211.936 us; speedup vs baseline: 1.1591x; 1.1591x over previous
//
#include <hip/hip_runtime.h>
#include <hip/hip_bf16.h>

#define NB 256
#define NR 100
#define ND 6168
#define DP 6272            // padded to 98 * 64
#define NH 128
#define NC 100
#define NSEG 98            // segments of K=64 ints
#define ABUF 32768         // 128 rows x 256 B
#define ROWB 24672         // ND*4 bytes per noise row
#define W1T_BYTES ((size_t)NH * DP * 2)

typedef __attribute__((ext_vector_type(8))) __bf16 bf16x8;
typedef __attribute__((ext_vector_type(4))) float f32x4;
typedef __attribute__((ext_vector_type(4))) int i32x4;
typedef __attribute__((ext_vector_type(4))) unsigned int u32x4;
typedef unsigned int u32;

typedef const __attribute__((address_space(1))) u32* gas_ptr;
typedef __attribute__((address_space(3))) u32* las_ptr;

__device__ __forceinline__ void gload16(const void* g, void* l) {
  __builtin_amdgcn_global_load_lds((gas_ptr)g, (las_ptr)l, 16, 0, 0);
}

#define SB() __builtin_amdgcn_sched_barrier(0)
// Barrier guaranteeing stage(s) landed: exactly 16 vmem ops are issued after
// stage(s) in steady state (bload(s-1)4, stage(s+1)4, bload(s)4, stage(s+2)4),
// so vmcnt(16) retires stage(s). lgkmcnt(0) orders LDS before rendezvous.
#define VBAR16() do { SB(); asm volatile("s_waitcnt vmcnt(16)"); SB(); \
  asm volatile("s_waitcnt lgkmcnt(0)"); SB(); __builtin_amdgcn_s_barrier(); SB(); } while (0)

// ---------- prep: W1 (ND,NH) f32 -> W1T (NH, DP) bf16, zero-padded ----------
__global__ void prep_w1t(const float* __restrict__ W1, __hip_bfloat16* __restrict__ W1T) {
  __shared__ float tile[32][NH + 1];
  const int d0 = blockIdx.x * 32;
  const int t = threadIdx.x;
#pragma unroll
  for (int p = 0; p < 16; ++p) {
    int idx = p * 256 + t;
    int dd = idx >> 7;
    int h  = idx & 127;
    int d  = d0 + dd;
    tile[dd][h] = (d < ND) ? W1[d * NH + h] : 0.f;
  }
  __syncthreads();
#pragma unroll
  for (int p = 0; p < 16; ++p) {
    int idx = p * 256 + t;
    int h  = idx >> 5;
    int dd = idx & 31;
    W1T[h * DP + d0 + dd] = __float2bfloat16(tile[dd][h]);
  }
}

// ---------- main: one block per b, 512 threads (8 waves, 2/SIMD) ----------
// LDS: [0,12544) xpair; [12544, 12544+4*32768) A buffers (4-deep rotation).
// Epilogue overlay at 0: hpart [2][128] f32, hbar [128] f32 at +1024.
__launch_bounds__(512, 2)
__global__ void fused_main(const int* __restrict__ x,
                           const int* __restrict__ noise,
                           const __hip_bfloat16* __restrict__ W1T,
                           const float* __restrict__ b1,
                           const float* __restrict__ W2,
                           const float* __restrict__ b2,
                           float* __restrict__ out) {
  __shared__ __align__(16) char lds[12544 + 4 * ABUF];
  u32* xpair = (u32*)lds;
  char* const Ab = lds + 12544;

  const int tid  = threadIdx.x;
  const int lane = tid & 63;
  const int w    = tid >> 6;      // 0..7
  const int wm   = w >> 2;        // row half (64 rows)
  const int wn   = w & 3;         // col quarter (32 h-cols)
  const int lq   = lane >> 4;
  const int lm   = lane & 15;
  const int b    = blockIdx.x;

  // ---- per-thread invariant staging descriptors (4 DMA calls/segment) ----
  const char* nsrc[4];   // global base (row + swizzled slot), seg 0
  u32 offmax[4];         // per-lane clamp so reads stay inside the row
  int dofs[4];           // LDS byte offset within an A buffer
  {
    const size_t nb = (size_t)b * NR * ND;
#pragma unroll
    for (int i = 0; i < 4; ++i) {
      int c   = w * 4 + i;              // call 0..31, covers rows 4c..4c+3
      int row = c * 4 + (lane >> 4);    // staged row 0..127
      int gr  = (row < NR) ? row : (NR - 1);
      int sg  = (lane & 15) ^ (row & 7);    // swizzled source slot
      nsrc[i]   = (const char*)(noise + nb + (size_t)gr * ND) + sg * 16;
      offmax[i] = (u32)(ROWB - 16 - sg * 16);
      dofs[i]   = c * 1024;             // + lane*16 applied by hardware
    }
  }
  const __hip_bfloat16* wsrc0 = W1T + (size_t)(wn * 32 + lm) * DP + lq * 8;
  const __hip_bfloat16* wsrc1 = W1T + (size_t)(wn * 32 + 16 + lm) * DP + lq * 8;

  f32x4 acc[4][2] = {};
  struct Bregs { bf16x8 f[4]; };   // [kt*2+nf], statically indexed
  Bregs Bcur, Bnxt;

  auto STAGE = [&](int ss, int bufidx) {
    char* dstb = Ab + bufidx * ABUF;
    const u32 off = (u32)(ss * 256);
#pragma unroll
    for (int i = 0; i < 4; ++i) {
      u32 o = (off > offmax[i]) ? offmax[i] : off;   // tail clamp (garbage -> B=0 cols)
      gload16(nsrc[i] + o, dstb + dofs[i]);
    }
  };

  auto BLOAD = [&](int s, Bregs& Br) {
#pragma unroll
    for (int kt = 0; kt < 2; ++kt) {
      Br.f[kt * 2 + 0] = *(const bf16x8*)(wsrc0 + s * 64 + kt * 32);
      Br.f[kt * 2 + 1] = *(const bf16x8*)(wsrc1 + s * 64 + kt * 32);
    }
  };

  auto COMPUTE = [&](int s, const char* A, const Bregs& Br) {
#pragma unroll
    for (int kt = 0; kt < 2; ++kt) {
      u32x4 xp = *(const u32x4*)(xpair + s * 32 + kt * 16 + lq * 4);
#pragma unroll
      for (int mf = 0; mf < 4; ++mf) {
        const int row  = wm * 64 + mf * 16 + lm;
        const int off0 = row * 256 + (((kt * 8 + lq * 2) ^ (row & 7)) * 16);
        i32x4 v0 = *(const i32x4*)(A + off0);
        i32x4 v1 = *(const i32x4*)(A + (off0 ^ 16));
        u32 q0 = (((u32)v0[0] | ((u32)v0[1] << 16)) ^ xp[0]) * 0x3F80u;
        u32 q1 = (((u32)v0[2] | ((u32)v0[3] << 16)) ^ xp[1]) * 0x3F80u;
        u32 q2 = (((u32)v1[0] | ((u32)v1[1] << 16)) ^ xp[2]) * 0x3F80u;
        u32 q3 = (((u32)v1[2] | ((u32)v1[3] << 16)) ^ xp[3]) * 0x3F80u;
        u32x4 pkv = {q0, q1, q2, q3};
        bf16x8 af = *(bf16x8*)&pkv;
        acc[mf][0] = __builtin_amdgcn_mfma_f32_16x16x32_bf16(af, Br.f[kt * 2 + 0], acc[mf][0], 0, 0, 0);
        acc[mf][1] = __builtin_amdgcn_mfma_f32_16x16x32_bf16(af, Br.f[kt * 2 + 1], acc[mf][1], 0, 0, 0);
      }
    }
  };

  // ---- prologue: stage 3 segments deep, bload(0), fill xpair, full drain ----
  STAGE(0, 0);
  STAGE(1, 1);
  STAGE(2, 2);
  BLOAD(0, Bcur);
  {
    const int* xb = x + b * ND;
    for (int i = tid; i < DP / 2; i += 512) {
      u32 p = 0;
      if (2 * i + 1 < ND) {
        int2 v = *(const int2*)(xb + 2 * i);
        p = ((u32)v.x & 1u) | (((u32)v.y & 1u) << 16);
      }
      xpair[i] = p;
    }
  }
  __syncthreads();   // one-time full drain; xpair + stage(0..2) visible

  // ---- main loop: 49 iters x 2 segments; counted waits, no drains ----
#pragma unroll 1
  for (int s = 0; s < NSEG; s += 2) {
    {
      VBAR16();
      int sn = (s + 1 < NSEG) ? (s + 1) : (NSEG - 1);
      BLOAD(sn, Bnxt);
      SB();
      int sc = (s + 3 < NSEG) ? (s + 3) : (NSEG - 1);
      STAGE(sc, (s + 3) & 3);
      SB();
      COMPUTE(s, Ab + (s & 3) * ABUF, Bcur);
    }
    {
      VBAR16();
      int sn = (s + 2 < NSEG) ? (s + 2) : (NSEG - 1);
      BLOAD(sn, Bcur);
      SB();
      int sc = (s + 4 < NSEG) ? (s + 4) : (NSEG - 1);
      STAGE(sc, (s + 4) & 3);
      SB();
      COMPUTE(s + 1, Ab + ((s + 1) & 3) * ABUF, Bnxt);
    }
  }

  // ---- epilogue: mean over rows of tanh(acc + b1), then W2^T fold ----
  __syncthreads();
  float* hpart = (float*)lds;            // [2][128]
  float* hbar  = (float*)(lds + 1024);   // [128]
#pragma unroll
  for (int nf = 0; nf < 2; ++nf) {
    int hcol = wn * 32 + nf * 16 + lm;
    float bb = b1[hcol];
    float ssum = 0.f;
#pragma unroll
    for (int mf = 0; mf < 4; ++mf) {
#pragma unroll
      for (int rg = 0; rg < 4; ++rg) {
        int m = wm * 64 + mf * 16 + lq * 4 + rg;
        float tv = tanhf(acc[mf][nf][rg] + bb);
        ssum += (m < NR) ? tv : 0.f;
      }
    }
    ssum += __shfl_xor(ssum, 16, 64);
    ssum += __shfl_xor(ssum, 32, 64);
    if (lq == 0) hpart[wm * 128 + hcol] = ssum;
  }
  __syncthreads();
  if (tid < NH) hbar[tid] = (hpart[tid] + hpart[128 + tid]) * (1.0f / NR);
  __syncthreads();
  if (tid < NC) {
    float sacc = b2[tid];
#pragma unroll 8
    for (int h = 0; h < NH; ++h) sacc += hbar[h] * W2[h * NC + tid];
    out[b * NC + tid] = sacc;
  }
}

extern "C" void kernel_launch(void* const* d_in, const int* in_sizes, int n_in,
                              void* d_out, int out_size, void* d_ws, size_t ws_size,
                              hipStream_t stream) {
  (void)in_sizes; (void)n_in; (void)out_size; (void)ws_size;
  const int* x     = (const int*)d_in[0];
  const int* noise = (const int*)d_in[1];
  const float* W1  = (const float*)d_in[2];
  const float* b1  = (const float*)d_in[3];
  const float* W2  = (const float*)d_in[4];
  const float* b2  = (const float*)d_in[5];
  float* out = (float*)d_out;

  __hip_bfloat16* W1T = (__hip_bfloat16*)d_ws;

  prep_w1t<<<DP / 32, 256, 0, stream>>>(W1, W1T);
  fused_main<<<NB, 512, 0, stream>>>(x, noise, W1T, b1, W2, b2, out);
}